// Round 2
// baseline (159.577 us; speedup 1.0000x reference)
//
#include <hip/hip_runtime.h>

// MedSegNet texture features: 3x3 zero-padded window per (b,c,h,w):
//  contrast, energy, entropy, homogeneity -> martingale transform.
//
// R7: strip-4 (16 px/thread = 4 rows x 4 cols), two passes of the R6 2-row
// engine over a shared 6-row register file.
//  - read redundancy 2x -> 1.5x (67 -> 50 MB), waves 16K -> 8K with 6 loads
//    in flight per thread (bursty-MLP fix probe).
//  - middle rows' e/n column terms are recomputed in pass B instead of kept
//    (saves 24 VGPRs; logs are ~2% of runtime).
//  - R6 algebra kept: contrast = clamp(s2*K_CON, 1e-4, C_CON) (sqrt/div-free,
//    knee at s2=8e-6), mart(f) = fmax(f*exp(-0.5), 1e-4), homogeneity via
//    v_rcp_f32 (operand in [1,2], ~1ulp).
//  - store invariant from R4/R5: every nt dwordx4 store instruction covers
//    two contiguous, 512B-aligned 512B segments (whole 64B lines only).

#define Wd 128
#define Hd 128
#define HWd 16384

typedef float v4f __attribute__((ext_vector_type(4)));

#define EXPM05  0.60653065971263342f   // exp(-0.5)
#define C_OVER9 0.067392295523626f     // exp(-0.5)/9
#define K_CON   67392.295523626f       // exp(-0.5)/9e-6
#define C_CON   0.53913836419f         // (8/9)*exp(-0.5)  (contrast plateau)
#define M_LO    1e-4f

__global__ __launch_bounds__(256) void medseg_kernel(const float* __restrict__ x,
                                                     float* __restrict__ out) {
    int tid = blockIdx.x * 256 + threadIdx.x;
    int plane = tid >> 10;                // 1024 threads per plane: 32 row-quads x 32
    int rem = tid & 1023;
    int h4 = rem >> 5;                    // row-quad index, rows h..h+3
    int lane31 = rem & 31;
    int w0 = lane31 << 2;
    int h = h4 << 2;

    const float* xp = x + (size_t)plane * HWd;

    // 6 input rows h-1..h+4, 4 center cols each, zero-padded rows.
    // Only dr=0 (h4==0) and dr=5 (h4==31) can be out of range.
    v4f v[6];
#pragma unroll
    for (int dr = 0; dr < 6; ++dr) {
        int hh = h + dr - 1;
        if (hh < 0 || hh >= Hd) {
            v[dr] = (v4f){0.f, 0.f, 0.f, 0.f};
        } else {
            v[dr] = *reinterpret_cast<const v4f*>(xp + hh * Wd + w0);
        }
    }

    // halo columns from neighbor lanes (convergent). shfl distance 1 only
    // crosses the half-wave seam at lanes 31/32, which the edge masks
    // (lane31==0 / ==31) discard anyway.
    float r[6][6];
#pragma unroll
    for (int dr = 0; dr < 6; ++dr) {
        float left  = __shfl_up(v[dr].w, 1);
        float right = __shfl_down(v[dr].x, 1);
        r[dr][0] = (lane31 == 0)  ? 0.f : left;
        r[dr][1] = v[dr].x; r[dr][2] = v[dr].y; r[dr][3] = v[dr].z; r[dr][4] = v[dr].w;
        r[dr][5] = (lane31 == 31) ? 0.f : right;
    }

    size_t base0 = (size_t)plane * 4 * HWd + h * Wd + w0;

#pragma unroll
    for (int ps = 0; ps < 2; ++ps) {      // pass ps: output rows h+2ps, h+2ps+1
        // column sums for the two 3-row windows of this pass, sharing the
        // middle two rows' terms. Input rows r[2ps .. 2ps+3].
        float colS[2][6], colE[2][6], colN[2][6];
#pragma unroll
        for (int j = 0; j < 6; ++j) {
            float e[4], n[4];
#pragma unroll
            for (int dr = 0; dr < 4; ++dr) {
                float vv = r[2 * ps + dr][j];
                e[dr] = vv * vv;
                float cl = fmaxf(vv, 1e-6f);
                n[dr] = cl * __logf(cl);
            }
            float s12 = r[2 * ps + 1][j] + r[2 * ps + 2][j];
            float e12 = e[1] + e[2];
            float n12 = n[1] + n[2];
            colS[0][j] = r[2 * ps][j] + s12;  colS[1][j] = s12 + r[2 * ps + 3][j];
            colE[0][j] = e[0] + e12;          colE[1][j] = e12 + e[3];
            colN[0][j] = n[0] + n12;          colN[1][j] = n12 + n[3];
        }

#pragma unroll
        for (int rs = 0; rs < 2; ++rs) {   // output row h + 2ps + rs
            float con[4], ene[4], ent[4], hom[4];
#pragma unroll
            for (int i = 0; i < 4; ++i) {
                float sum = colS[rs][i] + colS[rs][i + 1] + colS[rs][i + 2];
                float E9  = colE[rs][i] + colE[rs][i + 1] + colE[rs][i + 2];
                float N9  = colN[rs][i] + colN[rs][i + 1] + colN[rs][i + 2];
                float m = sum * (1.f / 9.f);

                float s2 = fmaxf(fmaf(-m, sum, E9), 0.f);   // sum (v-m)^2

                float sa = 0.f;
#pragma unroll
                for (int dr = 0; dr < 3; ++dr) {
#pragma unroll
                    for (int dj = 0; dj < 3; ++dj)
                        sa += fabsf(r[2 * ps + rs + dr][i + dj] - m);
                }

                // contrast: clamp(s2*K, 1e-4, C_CON)  (knee at s2 = 8e-6)
                con[i] = fmaxf(fminf(s2 * K_CON, C_CON), M_LO);
                // energy / entropy: mean folded with exp(-0.5), lower clamp only
                ene[i] = fmaxf(E9 * C_OVER9, M_LO);
                ent[i] = fmaxf(N9 * -C_OVER9, M_LO);
                // homogeneity: 1/((9+sa)/9 + 1e-6), operand in [1,2] -> v_rcp
                float t = fmaf(sa, 1.f / 9.f, 1.f + 1e-6f);
                hom[i] = fmaxf(__builtin_amdgcn_rcpf(t) * EXPM05, M_LO);
            }
            size_t o = base0 + (size_t)(2 * ps + rs) * Wd;
            __builtin_nontemporal_store((v4f){con[0], con[1], con[2], con[3]},
                                        reinterpret_cast<v4f*>(out + o));
            __builtin_nontemporal_store((v4f){ene[0], ene[1], ene[2], ene[3]},
                                        reinterpret_cast<v4f*>(out + o + HWd));
            __builtin_nontemporal_store((v4f){ent[0], ent[1], ent[2], ent[3]},
                                        reinterpret_cast<v4f*>(out + o + 2 * HWd));
            __builtin_nontemporal_store((v4f){hom[0], hom[1], hom[2], hom[3]},
                                        reinterpret_cast<v4f*>(out + o + 3 * HWd));
        }
    }
}

extern "C" void kernel_launch(void* const* d_in, const int* in_sizes, int n_in,
                              void* d_out, int out_size, void* d_ws, size_t ws_size,
                              hipStream_t stream) {
    const float* x = (const float*)d_in[0];
    float* out = (float*)d_out;
    int n_planes = in_sizes[0] / HWd;            // B*C = 512
    int total_threads = n_planes * (HWd / 16);   // 16 px per thread
    int blocks = total_threads / 256;            // exact: 2048
    medseg_kernel<<<blocks, 256, 0, stream>>>(x, out);
}

// Round 3
// 156.278 us; speedup vs baseline: 1.0211x; 1.0211x over previous
//
#include <hip/hip_runtime.h>

// MedSegNet texture features: 3x3 zero-padded window per (b,c,h,w):
//  contrast, energy, entropy, homogeneity -> martingale transform.
//
// R8: single-variable A/B vs R7 — nontemporal stores -> plain cached stores.
//  Theory: kernel is store-drain-limited at ~1.7 TB/s on the NT path
//  (134 MB / 77 us), while the harness fill hits 6.6 TB/s with cached
//  stores in the same timed region. Output (134 MB) < L3 (256 MB), never
//  re-read by the kernel, so cached writes retire at L2 rate and drain to
//  HBM in the background.
//  Everything else identical to R7: strip-4 (16 px/thread = 4 rows x 4
//  cols), 6-row register file, shfl halo, sqrt/div-free feature algebra,
//  line-covered dwordx4 store layout.

#define Wd 128
#define Hd 128
#define HWd 16384

typedef float v4f __attribute__((ext_vector_type(4)));

#define EXPM05  0.60653065971263342f   // exp(-0.5)
#define C_OVER9 0.067392295523626f     // exp(-0.5)/9
#define K_CON   67392.295523626f       // exp(-0.5)/9e-6
#define C_CON   0.53913836419f         // (8/9)*exp(-0.5)  (contrast plateau)
#define M_LO    1e-4f

__global__ __launch_bounds__(256) void medseg_kernel(const float* __restrict__ x,
                                                     float* __restrict__ out) {
    int tid = blockIdx.x * 256 + threadIdx.x;
    int plane = tid >> 10;                // 1024 threads per plane: 32 row-quads x 32
    int rem = tid & 1023;
    int h4 = rem >> 5;                    // row-quad index, rows h..h+3
    int lane31 = rem & 31;
    int w0 = lane31 << 2;
    int h = h4 << 2;

    const float* xp = x + (size_t)plane * HWd;

    // 6 input rows h-1..h+4, 4 center cols each, zero-padded rows.
    v4f v[6];
#pragma unroll
    for (int dr = 0; dr < 6; ++dr) {
        int hh = h + dr - 1;
        if (hh < 0 || hh >= Hd) {
            v[dr] = (v4f){0.f, 0.f, 0.f, 0.f};
        } else {
            v[dr] = *reinterpret_cast<const v4f*>(xp + hh * Wd + w0);
        }
    }

    // halo columns from neighbor lanes (convergent).
    float r[6][6];
#pragma unroll
    for (int dr = 0; dr < 6; ++dr) {
        float left  = __shfl_up(v[dr].w, 1);
        float right = __shfl_down(v[dr].x, 1);
        r[dr][0] = (lane31 == 0)  ? 0.f : left;
        r[dr][1] = v[dr].x; r[dr][2] = v[dr].y; r[dr][3] = v[dr].z; r[dr][4] = v[dr].w;
        r[dr][5] = (lane31 == 31) ? 0.f : right;
    }

    size_t base0 = (size_t)plane * 4 * HWd + h * Wd + w0;

#pragma unroll
    for (int ps = 0; ps < 2; ++ps) {      // pass ps: output rows h+2ps, h+2ps+1
        float colS[2][6], colE[2][6], colN[2][6];
#pragma unroll
        for (int j = 0; j < 6; ++j) {
            float e[4], n[4];
#pragma unroll
            for (int dr = 0; dr < 4; ++dr) {
                float vv = r[2 * ps + dr][j];
                e[dr] = vv * vv;
                float cl = fmaxf(vv, 1e-6f);
                n[dr] = cl * __logf(cl);
            }
            float s12 = r[2 * ps + 1][j] + r[2 * ps + 2][j];
            float e12 = e[1] + e[2];
            float n12 = n[1] + n[2];
            colS[0][j] = r[2 * ps][j] + s12;  colS[1][j] = s12 + r[2 * ps + 3][j];
            colE[0][j] = e[0] + e12;          colE[1][j] = e12 + e[3];
            colN[0][j] = n[0] + n12;          colN[1][j] = n12 + n[3];
        }

#pragma unroll
        for (int rs = 0; rs < 2; ++rs) {   // output row h + 2ps + rs
            float con[4], ene[4], ent[4], hom[4];
#pragma unroll
            for (int i = 0; i < 4; ++i) {
                float sum = colS[rs][i] + colS[rs][i + 1] + colS[rs][i + 2];
                float E9  = colE[rs][i] + colE[rs][i + 1] + colE[rs][i + 2];
                float N9  = colN[rs][i] + colN[rs][i + 1] + colN[rs][i + 2];
                float m = sum * (1.f / 9.f);

                float s2 = fmaxf(fmaf(-m, sum, E9), 0.f);   // sum (v-m)^2

                float sa = 0.f;
#pragma unroll
                for (int dr = 0; dr < 3; ++dr) {
#pragma unroll
                    for (int dj = 0; dj < 3; ++dj)
                        sa += fabsf(r[2 * ps + rs + dr][i + dj] - m);
                }

                // contrast: clamp(s2*K, 1e-4, C_CON)  (knee at s2 = 8e-6)
                con[i] = fmaxf(fminf(s2 * K_CON, C_CON), M_LO);
                // energy / entropy: mean folded with exp(-0.5), lower clamp only
                ene[i] = fmaxf(E9 * C_OVER9, M_LO);
                ent[i] = fmaxf(N9 * -C_OVER9, M_LO);
                // homogeneity: 1/((9+sa)/9 + 1e-6), operand in [1,2] -> v_rcp
                float t = fmaf(sa, 1.f / 9.f, 1.f + 1e-6f);
                hom[i] = fmaxf(__builtin_amdgcn_rcpf(t) * EXPM05, M_LO);
            }
            size_t o = base0 + (size_t)(2 * ps + rs) * Wd;
            *reinterpret_cast<v4f*>(out + o)            = (v4f){con[0], con[1], con[2], con[3]};
            *reinterpret_cast<v4f*>(out + o + HWd)      = (v4f){ene[0], ene[1], ene[2], ene[3]};
            *reinterpret_cast<v4f*>(out + o + 2 * HWd)  = (v4f){ent[0], ent[1], ent[2], ent[3]};
            *reinterpret_cast<v4f*>(out + o + 3 * HWd)  = (v4f){hom[0], hom[1], hom[2], hom[3]};
        }
    }
}

extern "C" void kernel_launch(void* const* d_in, const int* in_sizes, int n_in,
                              void* d_out, int out_size, void* d_ws, size_t ws_size,
                              hipStream_t stream) {
    const float* x = (const float*)d_in[0];
    float* out = (float*)d_out;
    int n_planes = in_sizes[0] / HWd;            // B*C = 512
    int total_threads = n_planes * (HWd / 16);   // 16 px per thread
    int blocks = total_threads / 256;            // exact: 2048
    medseg_kernel<<<blocks, 256, 0, stream>>>(x, out);
}